// Round 3
// baseline (2993.921 us; speedup 1.0000x reference)
//
#include <hip/hip_runtime.h>

#define HH   51
#define H4   204
#define TSEQ 2048
#define FUT  64
#define TT   (TSEQ + FUT)   // 2112
#define RPB  16             // batch rows per block (2 blocks/CU)
#define NTH  896            // 14 waves: 13 compute + 1 aux (emit + x-prefetch)
#define HSTR 72             // halfs per hbuf row (144 B stride)

typedef _Float16 h8 __attribute__((ext_vector_type(8)));
typedef float    f4 __attribute__((ext_vector_type(4)));

#define LOG2E 1.44269504f
#define MFMA(a, b, c) __builtin_amdgcn_mfma_f32_16x16x32_f16(a, b, c, 0, 0, 0)

// L1 recurrence cell (CRITICAL PATH: feeds h1 for next step).
// Pre-scaled gate preacts: g = {-L*zi, -L*zf, -2L*zg, -L*zo}. 5 exp2 + 3 rcp.
__device__ __forceinline__ void act_cell(const f4 g, float cin, float* cout, float* hout) {
    const float ei = __builtin_amdgcn_exp2f(g[0]);
    const float ef = __builtin_amdgcn_exp2f(g[1]);
    const float eg = __builtin_amdgcn_exp2f(g[2]);
    const float eo = __builtin_amdgcn_exp2f(g[3]);
    const float A = 1.0f + ei, B = 1.0f + ef, G = 1.0f + eg, C = 1.0f + eo;
    const float rAB = __builtin_amdgcn_rcpf(A * B);
    const float ig = rAB * B;                                 // sigmoid(zi)
    const float fg = rAB * A;                                 // sigmoid(zf)
    const float rGC = __builtin_amdgcn_rcpf(G * C);
    const float og = rGC * G;                                 // sigmoid(zo)
    const float tg = __builtin_fmaf(2.0f, rGC * C, -1.0f);    // tanh(zg)
    const float c2 = __builtin_fmaf(fg, cin, ig * tg);
    const float ec = __builtin_amdgcn_exp2f(-2.0f * LOG2E * c2);
    const float th = __builtin_fmaf(2.0f, __builtin_amdgcn_rcpf(1.0f + ec), -1.0f);
    *cout = c2;
    *hout = og * th;
}

// Emit cell (OFF critical path — deferred across the barrier). Quad-paired
// reciprocal: ONE rcp recovers all four gates -> 5 exp2 + 2 rcp. Products
// bounded by ~1e14 (f32-safe); rcp rel-err ~1e-7.
__device__ __forceinline__ void act_emit(const f4 g, float cin, float* hout) {
    const float ei = __builtin_amdgcn_exp2f(g[0]);
    const float ef = __builtin_amdgcn_exp2f(g[1]);
    const float eg = __builtin_amdgcn_exp2f(g[2]);
    const float eo = __builtin_amdgcn_exp2f(g[3]);
    const float A = 1.0f + ei, B = 1.0f + ef, G = 1.0f + eg, C = 1.0f + eo;
    const float P1 = A * B, P2 = G * C;
    const float r = __builtin_amdgcn_rcpf(P1 * P2);
    const float rP2 = r * P2, rP1 = r * P1;
    const float ig = rP2 * B;                                 // 1/A
    const float fg = rP2 * A;                                 // 1/B
    const float og = rP1 * G;                                 // 1/C
    const float tg = __builtin_fmaf(2.0f, rP1 * C, -1.0f);    // 2/G - 1
    const float c2 = __builtin_fmaf(fg, cin, ig * tg);
    const float ec = __builtin_amdgcn_exp2f(-2.0f * LOG2E * c2);
    const float th = __builtin_fmaf(2.0f, __builtin_amdgcn_rcpf(1.0f + ec), -1.0f);
    *hout = og * th;
}

// Merged iteration i (P = i&1), SOFTWARE-PIPELINED:
//   1. issue ds_read of hbuf[P]
//   2. act_emit of the PENDING emit cell (G2d,c1d saved last iter, t=i-2)
//      -> trans work ready to issue right after the barrier, overlapping the
//      ds_read/MFMA latency. Writes part[P] (emit wave reads it at iter i+1).
//   3. MFMAs; save new pending (G2d=G2, c1d=c1)
//   4. act_cell (L1, critical) -> c1, h1(i+1) -> hbuf[P^1]
// Aux wave: emit out(i-3) from part[P^1] (written top of i-1, barrier'd), then
// x prefetch. ONE barrier per step.
#define MBODY(P, i)                                                                \
    do {                                                                           \
        if (is_comp) {                                                             \
            const h8 b0 = *(const h8*)&hbuf[P][nl][quad * 8];                      \
            const h8 b1 = *(const h8*)&hbuf[P][nl][32 + quad * 8];                 \
            float h2v;                                                             \
            act_emit(G2d, c1d, &h2v);                                              \
            part[P][cw][quad][nl] = h2v * wo;                                      \
            f4 G2 = {0.f, 0.f, 0.f, 0.f}, G1 = {0.f, 0.f, 0.f, 0.f};               \
            G2 = MFMA(W2[0], b0, G2); G2 = MFMA(W2[1], b1, G2);                    \
            G1 = MFMA(W1[0], b0, G1); G1 = MFMA(W1[1], b1, G1);                    \
            G2d = G2; c1d = c1;                                                    \
            float hv;                                                              \
            act_cell(G1, c1, &c1, &hv);                                            \
            if (kh < HH) hbuf[(P) ^ 1][nl][1 + kh] = (_Float16)hv;                 \
        } else if (w == wa && lane < RPB) {                                        \
            if ((i) >= 3) {                                                        \
                float s0 = bo, s1 = 0.f, s2 = 0.f, s3 = 0.f;                       \
                _Pragma("unroll")                                                  \
                for (int j = 0; j < 13; ++j) {                                     \
                    s0 += part[(P) ^ 1][j][0][lane];                               \
                    s1 += part[(P) ^ 1][j][1][lane];                               \
                    s2 += part[(P) ^ 1][j][2][lane];                               \
                    s3 += part[(P) ^ 1][j][3][lane];                               \
                }                                                                  \
                out[(size_t)(rb + lane) * TT + (i) - 3] = (s0 + s1) + (s2 + s3);   \
            }                                                                      \
            if ((i) + 1 < TSEQ) hbuf[(P) ^ 1][lane][0] = (_Float16)xnext;          \
            if ((i) + 2 < TSEQ) xnext = x[(size_t)(rb + lane) * TSEQ + (i) + 2];   \
        }                                                                          \
        __syncthreads();                                                           \
    } while (0)

__global__ __launch_bounds__(NTH, 8)
void lstm_kernel(const float* __restrict__ x,
                 const float* __restrict__ Wih1, const float* __restrict__ Whh1,
                 const float* __restrict__ bih1, const float* __restrict__ bhh1,
                 const float* __restrict__ Wih2, const float* __restrict__ Whh2,
                 const float* __restrict__ bih2, const float* __restrict__ bhh2,
                 const float* __restrict__ Wout, const float* __restrict__ bout,
                 float* __restrict__ out)
{
    // double-buffered B-operand: [buf][row][k]; k=0: x_t, 1..51: h1, 52,53: const 1 (bias hi/lo)
    __shared__ _Float16 hbuf[2][RPB][HSTR];
    // per-(tile,quad) partials of wout.h2, double-buffered: [buf][tile][quad][row]
    __shared__ float part[2][13][4][17];
    __shared__ float wouts[64];

    const int tid  = threadIdx.x;
    const int lane = tid & 63;
    const int w    = tid >> 6;        // physical wave id (SIMD = w & 3)
    const int quad = lane >> 4;       // 0..3
    const int nl   = lane & 15;       // batch row (B-operand n / C-D col)
    const int rb   = blockIdx.x * RPB;

    // Role rotation: 13 compute waves split 4-3-3-3 over SIMDs; co-resident
    // blocks (b, b+256) use different shifts -> 7/7/6/6 compute waves per SIMD.
    const int  rot     = (blockIdx.x >> 8) & 1;
    const int  cw      = w - rot;               // compute tile id if in [0,13)
    const bool is_comp = (cw >= 0) && (cw < 13);
    const int  wa      = rot ? 0 : 13;          // aux wave: emit + x-prefetch

    // ---------------- one-time init ----------------
    if (tid < 64) wouts[tid] = (tid < HH) ? Wout[tid] : 0.0f;
    for (int i = tid; i < 2 * RPB * HSTR; i += NTH) (&hbuf[0][0][0])[i] = (_Float16)0.0f;
    __syncthreads();
    if (tid < RPB) {
        hbuf[0][tid][0]  = (_Float16)x[(size_t)(rb + tid) * TSEQ];
        hbuf[0][tid][52] = (_Float16)1.0f;  hbuf[0][tid][53] = (_Float16)1.0f;
        hbuf[1][tid][52] = (_Float16)1.0f;  hbuf[1][tid][53] = (_Float16)1.0f;
    }
    const float bo = bout[0];

    // ---------------- weight A-fragments in registers (once) ----------------
    // compute wave cw owns gate m-tile cw: rows j' = 16cw..16cw+15 (j' = 4k+q interleave)
    // Gate rows pre-scaled so MFMA emits exp2-ready args: i,f,o by -log2e, g by -2 log2e.
    h8 W1[2], W2[2];
    if (is_comp) {
        const int jp = 16 * cw + nl;
        const int kk = jp >> 2, q = jp & 3;
        const bool valid = (jp < H4);
        const int jrow = q * HH + kk;        // original gate row
        const float sc = (q == 2) ? (-2.0f * LOG2E) : (-LOG2E);
        float b1 = 0.0f, b2 = 0.0f;
        if (valid) { b1 = sc * (bih1[jrow] + bhh1[jrow]); b2 = sc * (bih2[jrow] + bhh2[jrow]); }
        const _Float16 b1h = (_Float16)b1, b2h = (_Float16)b2;
        const _Float16 b1l = (_Float16)(b1 - (float)b1h), b2l = (_Float16)(b2 - (float)b2h);
        #pragma unroll
        for (int s = 0; s < 2; ++s) {
            h8 w1v, w2v;
            #pragma unroll
            for (int j = 0; j < 8; ++j) {
                const int k = s * 32 + quad * 8 + j;
                _Float16 a1 = (_Float16)0.0f, a2 = (_Float16)0.0f;
                if (valid) {
                    if (k == 0) {
                        a1 = (_Float16)(sc * Wih1[jrow]);
                    } else if (k <= HH) {
                        const int o = jrow * HH + (k - 1);
                        a1 = (_Float16)(sc * Whh1[o]);
                        a2 = (_Float16)(sc * (Wih2[o] + Whh2[o]));
                    } else if (k == 52) { a1 = b1h; a2 = b2h; }
                    else if (k == 53)   { a1 = b1l; a2 = b2l; }
                }
                w1v[j] = a1;
                w2v[j] = a2;
            }
            W1[s] = w1v;
            W2[s] = w2v;
        }
    }

    // x register pipeline (aux wave)
    float xnext = 0.0f;
    if (w == wa && lane < RPB) xnext = x[(size_t)(rb + lane) * TSEQ + 1];

    const int kh = 4 * cw + quad;     // hidden unit owned by this lane (if is_comp)
    float c1 = 0.0f;
    f4 G2d = {0.f, 0.f, 0.f, 0.f};    // pending emit-cell gate preacts
    float c1d = 0.0f;                 // pending emit-cell c input
    __syncthreads();
    const float wo = is_comp ? wouts[kh] : 0.0f;

    // ---------------- peel i = 0 : P1(0) only ----------------
    if (is_comp) {
        const h8 b0 = *(const h8*)&hbuf[0][nl][quad * 8];
        const h8 b1 = *(const h8*)&hbuf[0][nl][32 + quad * 8];
        f4 G1 = {0.f, 0.f, 0.f, 0.f};
        G1 = MFMA(W1[0], b0, G1); G1 = MFMA(W1[1], b1, G1);
        float hv;
        act_cell(G1, c1, &c1, &hv);
        if (kh < HH) hbuf[1][nl][1 + kh] = (_Float16)hv;
    } else if (w == wa && lane < RPB) {
        hbuf[1][lane][0] = (_Float16)xnext;               // x(1)
        xnext = x[(size_t)(rb + lane) * TSEQ + 2];        // x(2)
    }
    __syncthreads();

    // ---------------- peel i = 1 : save pending P2(0); act1 P1(1) ----------------
    if (is_comp) {
        const h8 b0 = *(const h8*)&hbuf[1][nl][quad * 8];
        const h8 b1 = *(const h8*)&hbuf[1][nl][32 + quad * 8];
        f4 G2 = {0.f, 0.f, 0.f, 0.f}, G1 = {0.f, 0.f, 0.f, 0.f};
        G2 = MFMA(W2[0], b0, G2); G2 = MFMA(W2[1], b1, G2);
        G1 = MFMA(W1[0], b0, G1); G1 = MFMA(W1[1], b1, G1);
        G2d = G2; c1d = c1;                               // pending t=0
        float hv;
        act_cell(G1, c1, &c1, &hv);
        if (kh < HH) hbuf[0][nl][1 + kh] = (_Float16)hv;  // h1(2)
    } else if (w == wa && lane < RPB) {
        hbuf[0][lane][0] = (_Float16)xnext;               // x(2)
        xnext = x[(size_t)(rb + lane) * TSEQ + 3];        // x(3)
    }
    __syncthreads();

    // ---------------- main: i = 2 .. TSEQ-1, unrolled x2 ----------------
    for (int i = 2; i < TSEQ; i += 2) {
        MBODY(0, i);
        MBODY(1, i + 1);
    }
    // state: P1 done through 2047 (h1 post-2047 in hbuf[0], c1 = c1(2047));
    // pending = P2(2046); part[1] = P2(2045); out emitted through 2044.

    // ---------------- drain: flush pending P2(TSEQ-2), emit out(TSEQ-3) ----------------
    if (is_comp) {
        float h2v;
        act_emit(G2d, c1d, &h2v);
        part[0][cw][quad][nl] = h2v * wo;                 // (TSEQ-2)&1 == 0
    } else if (w == wa && lane < RPB) {
        float s0 = bo, s1 = 0.f, s2 = 0.f, s3 = 0.f;
        #pragma unroll
        for (int j = 0; j < 13; ++j) {
            s0 += part[1][j][0][lane];
            s1 += part[1][j][1][lane];
            s2 += part[1][j][2][lane];
            s3 += part[1][j][3][lane];
        }
        out[(size_t)(rb + lane) * TT + (TSEQ - 3)] = (s0 + s1) + (s2 + s3);
    }
    __syncthreads();

    // ---------------- FUT tail: t = TSEQ-1 .. TT-1, explicit 3-phase ----------------
    for (int t = TSEQ - 1; t < TT; ++t) {
        const int pb = (t + 1) & 1;   // buffer holding h1 post-step-t (+ feedback x slot)
        if (is_comp) {
            // P2(t)
            const h8 b0 = *(const h8*)&hbuf[pb][nl][quad * 8];
            const h8 b1 = *(const h8*)&hbuf[pb][nl][32 + quad * 8];
            f4 G2 = {0.f, 0.f, 0.f, 0.f};
            G2 = MFMA(W2[0], b0, G2); G2 = MFMA(W2[1], b1, G2);
            float h2v;
            act_emit(G2, c1, &h2v);
            part[t & 1][cw][quad][nl] = h2v * wo;
        } else if (w == wa && t == TSEQ - 1 && lane < RPB) {
            // emit out(TSEQ-2) from the drain's part[0]
            float s0 = bo, s1 = 0.f, s2 = 0.f, s3 = 0.f;
            #pragma unroll
            for (int j = 0; j < 13; ++j) {
                s0 += part[0][j][0][lane];
                s1 += part[0][j][1][lane];
                s2 += part[0][j][2][lane];
                s3 += part[0][j][3][lane];
            }
            out[(size_t)(rb + lane) * TT + (TSEQ - 2)] = (s0 + s1) + (s2 + s3);
        }
        __syncthreads();
        if (w == wa && lane < RPB) {
            float s0 = bo, s1 = 0.f, s2 = 0.f, s3 = 0.f;
            #pragma unroll
            for (int j = 0; j < 13; ++j) {
                s0 += part[t & 1][j][0][lane];
                s1 += part[t & 1][j][1][lane];
                s2 += part[t & 1][j][2][lane];
                s3 += part[t & 1][j][3][lane];
            }
            const float s = (s0 + s1) + (s2 + s3);
            out[(size_t)(rb + lane) * TT + t] = s;
            if (t + 1 < TT) hbuf[pb][lane][0] = (_Float16)s;   // autoregressive x(t+1)
        }
        __syncthreads();
        if (t + 1 < TT) {
            if (is_comp) {
                // P1(t+1): reads hbuf[pb] (h1 post-t + feedback x), writes h1 post-(t+1)
                const h8 b0 = *(const h8*)&hbuf[pb][nl][quad * 8];
                const h8 b1 = *(const h8*)&hbuf[pb][nl][32 + quad * 8];
                f4 G1 = {0.f, 0.f, 0.f, 0.f};
                G1 = MFMA(W1[0], b0, G1); G1 = MFMA(W1[1], b1, G1);
                float hv;
                act_cell(G1, c1, &c1, &hv);
                if (kh < HH) hbuf[pb ^ 1][nl][1 + kh] = (_Float16)hv;
            }
            __syncthreads();
        }
    }
}

extern "C" void kernel_launch(void* const* d_in, const int* in_sizes, int n_in,
                              void* d_out, int out_size, void* d_ws, size_t ws_size,
                              hipStream_t stream) {
    (void)in_sizes; (void)n_in; (void)d_ws; (void)ws_size; (void)out_size;
    const float* x    = (const float*)d_in[0];
    const float* Wih1 = (const float*)d_in[1];
    const float* Whh1 = (const float*)d_in[2];
    const float* bih1 = (const float*)d_in[3];
    const float* bhh1 = (const float*)d_in[4];
    const float* Wih2 = (const float*)d_in[5];
    const float* Whh2 = (const float*)d_in[6];
    const float* bih2 = (const float*)d_in[7];
    const float* bhh2 = (const float*)d_in[8];
    const float* Wout = (const float*)d_in[9];
    const float* bout = (const float*)d_in[10];
    float* outp = (float*)d_out;

    dim3 grid(8192 / RPB);   // 512 blocks, 2 per CU
    dim3 block(NTH);
    hipLaunchKernelGGL(lstm_kernel, grid, block, 0, stream,
                       x, Wih1, Whh1, bih1, bhh1, Wih2, Whh2, bih2, bhh2,
                       Wout, bout, outp);
}

// Round 4
// 2697.434 us; speedup vs baseline: 1.1099x; 1.1099x over previous
//
#include <hip/hip_runtime.h>

#define HH   51
#define H4   204
#define TSEQ 2048
#define FUT  64
#define TT   (TSEQ + FUT)   // 2112
#define RPB  16             // batch rows per block (2 blocks/CU)
#define NTH  1024           // 16 waves: 13 compute + 1 aux + 2 idle (1024 = proven 2-block packing)
#define HSTR 72             // halfs per hbuf row (144 B stride)

typedef _Float16 h8 __attribute__((ext_vector_type(8)));
typedef float    f4 __attribute__((ext_vector_type(4)));

#define LOG2E 1.44269504f
#define MFMA(a, b, c) __builtin_amdgcn_mfma_f32_16x16x32_f16(a, b, c, 0, 0, 0)

// L1 recurrence cell (CRITICAL PATH: feeds h1 for next step).
// Pre-scaled gate preacts: g = {-L*zi, -L*zf, -2L*zg, -L*zo}. 5 exp2 + 3 rcp.
__device__ __forceinline__ void act_cell(const f4 g, float cin, float* cout, float* hout) {
    const float ei = __builtin_amdgcn_exp2f(g[0]);
    const float ef = __builtin_amdgcn_exp2f(g[1]);
    const float eg = __builtin_amdgcn_exp2f(g[2]);
    const float eo = __builtin_amdgcn_exp2f(g[3]);
    const float A = 1.0f + ei, B = 1.0f + ef, G = 1.0f + eg, C = 1.0f + eo;
    const float rAB = __builtin_amdgcn_rcpf(A * B);
    const float ig = rAB * B;                                 // sigmoid(zi)
    const float fg = rAB * A;                                 // sigmoid(zf)
    const float rGC = __builtin_amdgcn_rcpf(G * C);
    const float og = rGC * G;                                 // sigmoid(zo)
    const float tg = __builtin_fmaf(2.0f, rGC * C, -1.0f);    // tanh(zg)
    const float c2 = __builtin_fmaf(fg, cin, ig * tg);
    const float ec = __builtin_amdgcn_exp2f(-2.0f * LOG2E * c2);
    const float th = __builtin_fmaf(2.0f, __builtin_amdgcn_rcpf(1.0f + ec), -1.0f);
    *cout = c2;
    *hout = og * th;
}

// Emit cell (OFF critical path — deferred across the barrier). Quad-paired
// reciprocal: ONE rcp recovers all four gates -> 5 exp2 + 2 rcp.
__device__ __forceinline__ void act_emit(const f4 g, float cin, float* hout) {
    const float ei = __builtin_amdgcn_exp2f(g[0]);
    const float ef = __builtin_amdgcn_exp2f(g[1]);
    const float eg = __builtin_amdgcn_exp2f(g[2]);
    const float eo = __builtin_amdgcn_exp2f(g[3]);
    const float A = 1.0f + ei, B = 1.0f + ef, G = 1.0f + eg, C = 1.0f + eo;
    const float P1 = A * B, P2 = G * C;
    const float r = __builtin_amdgcn_rcpf(P1 * P2);
    const float rP2 = r * P2, rP1 = r * P1;
    const float ig = rP2 * B;                                 // 1/A
    const float fg = rP2 * A;                                 // 1/B
    const float og = rP1 * G;                                 // 1/C
    const float tg = __builtin_fmaf(2.0f, rP1 * C, -1.0f);    // 2/G - 1
    const float c2 = __builtin_fmaf(fg, cin, ig * tg);
    const float ec = __builtin_amdgcn_exp2f(-2.0f * LOG2E * c2);
    const float th = __builtin_fmaf(2.0f, __builtin_amdgcn_rcpf(1.0f + ec), -1.0f);
    *hout = og * th;
}

// Merged iteration i (P = i&1), SOFTWARE-PIPELINED:
//   1. issue ds_read of hbuf[P]
//   2. act_emit of the PENDING emit cell (G2d,c1d saved last iter, t=i-2)
//      -> trans work ready to issue right after the barrier, overlapping the
//      ds_read/MFMA latency. Writes part[P] (aux wave reads it at iter i+1).
//   3. MFMAs; save new pending (G2d=G2, c1d=c1)
//   4. act_cell (L1, critical) -> c1, h1(i+1) -> hbuf[P^1]
// Aux wave: emit out(i-3) from part[P^1] (written top of i-1, barrier'd), then
// x prefetch. ONE barrier per step.
#define MBODY(P, i)                                                                \
    do {                                                                           \
        if (is_comp) {                                                             \
            const h8 b0 = *(const h8*)&hbuf[P][nl][quad * 8];                      \
            const h8 b1 = *(const h8*)&hbuf[P][nl][32 + quad * 8];                 \
            float h2v;                                                             \
            act_emit(G2d, c1d, &h2v);                                              \
            part[P][cw][quad][nl] = h2v * wo;                                      \
            f4 G2 = {0.f, 0.f, 0.f, 0.f}, G1 = {0.f, 0.f, 0.f, 0.f};               \
            G2 = MFMA(W2[0], b0, G2); G2 = MFMA(W2[1], b1, G2);                    \
            G1 = MFMA(W1[0], b0, G1); G1 = MFMA(W1[1], b1, G1);                    \
            G2d = G2; c1d = c1;                                                    \
            float hv;                                                              \
            act_cell(G1, c1, &c1, &hv);                                            \
            if (kh < HH) hbuf[(P) ^ 1][nl][1 + kh] = (_Float16)hv;                 \
        } else if (w == wa && lane < RPB) {                                        \
            if ((i) >= 3) {                                                        \
                float s0 = bo, s1 = 0.f, s2 = 0.f, s3 = 0.f;                       \
                _Pragma("unroll")                                                  \
                for (int j = 0; j < 13; ++j) {                                     \
                    s0 += part[(P) ^ 1][j][0][lane];                               \
                    s1 += part[(P) ^ 1][j][1][lane];                               \
                    s2 += part[(P) ^ 1][j][2][lane];                               \
                    s3 += part[(P) ^ 1][j][3][lane];                               \
                }                                                                  \
                out[(size_t)(rb + lane) * TT + (i) - 3] = (s0 + s1) + (s2 + s3);   \
            }                                                                      \
            if ((i) + 1 < TSEQ) hbuf[(P) ^ 1][lane][0] = (_Float16)xnext;          \
            if ((i) + 2 < TSEQ) xnext = x[(size_t)(rb + lane) * TSEQ + (i) + 2];   \
        }                                                                          \
        __syncthreads();                                                           \
    } while (0)

__global__ __launch_bounds__(NTH, 8)
void lstm_kernel(const float* __restrict__ x,
                 const float* __restrict__ Wih1, const float* __restrict__ Whh1,
                 const float* __restrict__ bih1, const float* __restrict__ bhh1,
                 const float* __restrict__ Wih2, const float* __restrict__ Whh2,
                 const float* __restrict__ bih2, const float* __restrict__ bhh2,
                 const float* __restrict__ Wout, const float* __restrict__ bout,
                 float* __restrict__ out)
{
    // double-buffered B-operand: [buf][row][k]; k=0: x_t, 1..51: h1, 52,53: const 1 (bias hi/lo)
    __shared__ _Float16 hbuf[2][RPB][HSTR];
    // per-(tile,quad) partials of wout.h2, double-buffered: [buf][tile][quad][row]
    __shared__ float part[2][13][4][17];
    __shared__ float wouts[64];

    const int tid  = threadIdx.x;
    const int lane = tid & 63;
    const int w    = tid >> 6;        // physical wave id (SIMD = w & 3)
    const int quad = lane >> 4;       // 0..3
    const int nl   = lane & 15;       // batch row (B-operand n / C-D col)
    const int rb   = blockIdx.x * RPB;

    // Role rotation: 13 compute waves split 4-3-3-3 over SIMDs; co-resident
    // blocks (b, b+256) use shifts 0 / 3 -> combined 7/6/6/7 per SIMD.
    const int  rot     = (blockIdx.x >> 8) & 1;
    const int  cw      = w - (rot ? 3 : 0);     // compute tile id if in [0,13)
    const bool is_comp = (cw >= 0) && (cw < 13);
    const int  wa      = rot ? 0 : 13;          // aux wave: emit + x-prefetch

    // ---------------- one-time init ----------------
    if (tid < 64) wouts[tid] = (tid < HH) ? Wout[tid] : 0.0f;
    for (int i = tid; i < 2 * RPB * HSTR; i += NTH) (&hbuf[0][0][0])[i] = (_Float16)0.0f;
    __syncthreads();
    if (tid < RPB) {
        hbuf[0][tid][0]  = (_Float16)x[(size_t)(rb + tid) * TSEQ];
        hbuf[0][tid][52] = (_Float16)1.0f;  hbuf[0][tid][53] = (_Float16)1.0f;
        hbuf[1][tid][52] = (_Float16)1.0f;  hbuf[1][tid][53] = (_Float16)1.0f;
    }
    const float bo = bout[0];

    // ---------------- weight A-fragments in registers (once) ----------------
    // compute wave cw owns gate m-tile cw: rows j' = 16cw..16cw+15 (j' = 4k+q interleave)
    // Gate rows pre-scaled so MFMA emits exp2-ready args: i,f,o by -log2e, g by -2 log2e.
    h8 W1[2], W2[2];
    if (is_comp) {
        const int jp = 16 * cw + nl;
        const int kk = jp >> 2, q = jp & 3;
        const bool valid = (jp < H4);
        const int jrow = q * HH + kk;        // original gate row
        const float sc = (q == 2) ? (-2.0f * LOG2E) : (-LOG2E);
        float b1 = 0.0f, b2 = 0.0f;
        if (valid) { b1 = sc * (bih1[jrow] + bhh1[jrow]); b2 = sc * (bih2[jrow] + bhh2[jrow]); }
        const _Float16 b1h = (_Float16)b1, b2h = (_Float16)b2;
        const _Float16 b1l = (_Float16)(b1 - (float)b1h), b2l = (_Float16)(b2 - (float)b2h);
        #pragma unroll
        for (int s = 0; s < 2; ++s) {
            h8 w1v, w2v;
            #pragma unroll
            for (int j = 0; j < 8; ++j) {
                const int k = s * 32 + quad * 8 + j;
                _Float16 a1 = (_Float16)0.0f, a2 = (_Float16)0.0f;
                if (valid) {
                    if (k == 0) {
                        a1 = (_Float16)(sc * Wih1[jrow]);
                    } else if (k <= HH) {
                        const int o = jrow * HH + (k - 1);
                        a1 = (_Float16)(sc * Whh1[o]);
                        a2 = (_Float16)(sc * (Wih2[o] + Whh2[o]));
                    } else if (k == 52) { a1 = b1h; a2 = b2h; }
                    else if (k == 53)   { a1 = b1l; a2 = b2l; }
                }
                w1v[j] = a1;
                w2v[j] = a2;
            }
            W1[s] = w1v;
            W2[s] = w2v;
        }
    }

    // x register pipeline (aux wave)
    float xnext = 0.0f;
    if (w == wa && lane < RPB) xnext = x[(size_t)(rb + lane) * TSEQ + 1];

    const int kh = 4 * cw + quad;     // hidden unit owned by this lane (if is_comp)
    float c1 = 0.0f;
    f4 G2d = {0.f, 0.f, 0.f, 0.f};    // pending emit-cell gate preacts
    float c1d = 0.0f;                 // pending emit-cell c input
    __syncthreads();
    const float wo = is_comp ? wouts[kh] : 0.0f;

    // ---------------- peel i = 0 : P1(0) only ----------------
    if (is_comp) {
        const h8 b0 = *(const h8*)&hbuf[0][nl][quad * 8];
        const h8 b1 = *(const h8*)&hbuf[0][nl][32 + quad * 8];
        f4 G1 = {0.f, 0.f, 0.f, 0.f};
        G1 = MFMA(W1[0], b0, G1); G1 = MFMA(W1[1], b1, G1);
        float hv;
        act_cell(G1, c1, &c1, &hv);
        if (kh < HH) hbuf[1][nl][1 + kh] = (_Float16)hv;
    } else if (w == wa && lane < RPB) {
        hbuf[1][lane][0] = (_Float16)xnext;               // x(1)
        xnext = x[(size_t)(rb + lane) * TSEQ + 2];        // x(2)
    }
    __syncthreads();

    // ---------------- peel i = 1 : save pending P2(0); act1 P1(1) ----------------
    if (is_comp) {
        const h8 b0 = *(const h8*)&hbuf[1][nl][quad * 8];
        const h8 b1 = *(const h8*)&hbuf[1][nl][32 + quad * 8];
        f4 G2 = {0.f, 0.f, 0.f, 0.f}, G1 = {0.f, 0.f, 0.f, 0.f};
        G2 = MFMA(W2[0], b0, G2); G2 = MFMA(W2[1], b1, G2);
        G1 = MFMA(W1[0], b0, G1); G1 = MFMA(W1[1], b1, G1);
        G2d = G2; c1d = c1;                               // pending t=0
        float hv;
        act_cell(G1, c1, &c1, &hv);
        if (kh < HH) hbuf[0][nl][1 + kh] = (_Float16)hv;  // h1(2)
    } else if (w == wa && lane < RPB) {
        hbuf[0][lane][0] = (_Float16)xnext;               // x(2)
        xnext = x[(size_t)(rb + lane) * TSEQ + 3];        // x(3)
    }
    __syncthreads();

    // ---------------- main: i = 2 .. TSEQ-1, unrolled x2 ----------------
    for (int i = 2; i < TSEQ; i += 2) {
        MBODY(0, i);
        MBODY(1, i + 1);
    }
    // state: P1 done through 2047 (h1 post-2047 in hbuf[0], c1 = c1(2047));
    // pending = P2(2046); part[1] = P2(2045); out emitted through 2044.

    // ---------------- drain: flush pending P2(TSEQ-2), emit out(TSEQ-3) ----------------
    if (is_comp) {
        float h2v;
        act_emit(G2d, c1d, &h2v);
        part[0][cw][quad][nl] = h2v * wo;                 // (TSEQ-2)&1 == 0
    } else if (w == wa && lane < RPB) {
        float s0 = bo, s1 = 0.f, s2 = 0.f, s3 = 0.f;
        #pragma unroll
        for (int j = 0; j < 13; ++j) {
            s0 += part[1][j][0][lane];
            s1 += part[1][j][1][lane];
            s2 += part[1][j][2][lane];
            s3 += part[1][j][3][lane];
        }
        out[(size_t)(rb + lane) * TT + (TSEQ - 3)] = (s0 + s1) + (s2 + s3);
    }
    __syncthreads();

    // ---------------- FUT tail: t = TSEQ-1 .. TT-1, explicit 3-phase ----------------
    for (int t = TSEQ - 1; t < TT; ++t) {
        const int pb = (t + 1) & 1;   // buffer holding h1 post-step-t (+ feedback x slot)
        if (is_comp) {
            // P2(t)
            const h8 b0 = *(const h8*)&hbuf[pb][nl][quad * 8];
            const h8 b1 = *(const h8*)&hbuf[pb][nl][32 + quad * 8];
            f4 G2 = {0.f, 0.f, 0.f, 0.f};
            G2 = MFMA(W2[0], b0, G2); G2 = MFMA(W2[1], b1, G2);
            float h2v;
            act_emit(G2, c1, &h2v);
            part[t & 1][cw][quad][nl] = h2v * wo;
        } else if (w == wa && t == TSEQ - 1 && lane < RPB) {
            // emit out(TSEQ-2) from the drain's part[0]
            float s0 = bo, s1 = 0.f, s2 = 0.f, s3 = 0.f;
            #pragma unroll
            for (int j = 0; j < 13; ++j) {
                s0 += part[0][j][0][lane];
                s1 += part[0][j][1][lane];
                s2 += part[0][j][2][lane];
                s3 += part[0][j][3][lane];
            }
            out[(size_t)(rb + lane) * TT + (TSEQ - 2)] = (s0 + s1) + (s2 + s3);
        }
        __syncthreads();
        if (w == wa && lane < RPB) {
            float s0 = bo, s1 = 0.f, s2 = 0.f, s3 = 0.f;
            #pragma unroll
            for (int j = 0; j < 13; ++j) {
                s0 += part[t & 1][j][0][lane];
                s1 += part[t & 1][j][1][lane];
                s2 += part[t & 1][j][2][lane];
                s3 += part[t & 1][j][3][lane];
            }
            const float s = (s0 + s1) + (s2 + s3);
            out[(size_t)(rb + lane) * TT + t] = s;
            if (t + 1 < TT) hbuf[pb][lane][0] = (_Float16)s;   // autoregressive x(t+1)
        }
        __syncthreads();
        if (t + 1 < TT) {
            if (is_comp) {
                // P1(t+1): reads hbuf[pb] (h1 post-t + feedback x), writes h1 post-(t+1)
                const h8 b0 = *(const h8*)&hbuf[pb][nl][quad * 8];
                const h8 b1 = *(const h8*)&hbuf[pb][nl][32 + quad * 8];
                f4 G1 = {0.f, 0.f, 0.f, 0.f};
                G1 = MFMA(W1[0], b0, G1); G1 = MFMA(W1[1], b1, G1);
                float hv;
                act_cell(G1, c1, &c1, &hv);
                if (kh < HH) hbuf[pb ^ 1][nl][1 + kh] = (_Float16)hv;
            }
            __syncthreads();
        }
    }
}

extern "C" void kernel_launch(void* const* d_in, const int* in_sizes, int n_in,
                              void* d_out, int out_size, void* d_ws, size_t ws_size,
                              hipStream_t stream) {
    (void)in_sizes; (void)n_in; (void)d_ws; (void)ws_size; (void)out_size;
    const float* x    = (const float*)d_in[0];
    const float* Wih1 = (const float*)d_in[1];
    const float* Whh1 = (const float*)d_in[2];
    const float* bih1 = (const float*)d_in[3];
    const float* bhh1 = (const float*)d_in[4];
    const float* Wih2 = (const float*)d_in[5];
    const float* Whh2 = (const float*)d_in[6];
    const float* bih2 = (const float*)d_in[7];
    const float* bhh2 = (const float*)d_in[8];
    const float* Wout = (const float*)d_in[9];
    const float* bout = (const float*)d_in[10];
    float* outp = (float*)d_out;

    dim3 grid(8192 / RPB);   // 512 blocks, 2 per CU
    dim3 block(NTH);
    hipLaunchKernelGGL(lstm_kernel, grid, block, 0, stream,
                       x, Wih1, Whh1, bih1, bhh1, Wih2, Whh2, bih2, bhh2,
                       Wout, bout, outp);
}

// Round 6
// 2497.122 us; speedup vs baseline: 1.1989x; 1.0802x over previous
//
#include <hip/hip_runtime.h>

#define HH   51
#define H4   204
#define TSEQ 2048
#define FUT  64
#define TT   (TSEQ + FUT)   // 2112
#define RPB  16             // batch rows per block (2 blocks/CU)
#define NTH  1024           // 16 waves: 13 compute + emit + prefetch + 1 idle (proven 2-block packing)
#define HSTR 72             // halfs per hbuf row (144 B stride)

typedef _Float16 h8 __attribute__((ext_vector_type(8)));
typedef float    f4 __attribute__((ext_vector_type(4)));

#define LOG2E 1.44269504f
#define MFMA(a, b, c) __builtin_amdgcn_mfma_f32_16x16x32_f16(a, b, c, 0, 0, 0)

// LSTM-cell nonlinearity, 6 transcendentals (was 8).
// Pre-scaled gate preacts (scales folded into f16 weights at load):
//   g[0]=-L*zi, g[1]=-L*zf, g[2]=-2L*zg, g[3]=-L*zo  (L = log2 e)
// With A=1+e^-zi, B=1+e^-zf, G=1+e^-2zg, C=1+e^-zo and ONE shared
// r = rcp(A*B*G*C):
//   f        = r*(A*G*C)
//   i*tanh(g)= r*(B*C)*(2-G)      <- product form: sigma(i),tanh(g) never split
//   o        = r*(A*B*G)
//   c2       = r*fma(A*GC, cin, BC*(2-G))
// Then tanh(c2) costs the remaining exp2+rcp. Range-safe: |z|<~5 -> ABGC<e^30.
__device__ __forceinline__ void act6(const f4 g, float cin, float* cout, float* hout) {
    const float ei = __builtin_amdgcn_exp2f(g[0]);
    const float ef = __builtin_amdgcn_exp2f(g[1]);
    const float eg = __builtin_amdgcn_exp2f(g[2]);
    const float eo = __builtin_amdgcn_exp2f(g[3]);
    const float A = 1.0f + ei, B = 1.0f + ef, G = 1.0f + eg, C = 1.0f + eo;
    const float AB = A * B, GC = G * C;
    const float r  = __builtin_amdgcn_rcpf(AB * GC);
    const float t1 = A * GC;                      // -> f = r*t1
    const float t4 = (B * C) * (2.0f - G);        // -> i*tanh(g) = r*t4
    const float c2 = r * __builtin_fmaf(t1, cin, t4);
    const float og = r * (AB * G);                // sigmoid(zo)
    const float ec = __builtin_amdgcn_exp2f(-2.0f * LOG2E * c2);
    const float th = __builtin_fmaf(2.0f, __builtin_amdgcn_rcpf(1.0f + ec), -1.0f);
    *cout = c2;
    *hout = og * th;
}

// Merged iteration i (parity P = i&1): P2(i-1) + P1(i) back-to-back (R2
// skeleton: both consume hbuf[P], ONE ds_read pair feeds all 4 MFMAs; the two
// activation chains are independent -> ILP). P1 writes h1(i+1) -> hbuf[P^1];
// P2 writes weighted h2 partial to part[P^1]; emit wave sums part[P] for
// out(i-2). ONE barrier per step.
#define MERGED_BODY(P, EMIT_IDX, DO_EMIT, XI)                                      \
    do {                                                                           \
        if (is_comp) {                                                             \
            const h8 b0 = *(const h8*)&hbuf[P][nl][quad * 8];                      \
            const h8 b1 = *(const h8*)&hbuf[P][nl][32 + quad * 8];                 \
            f4 G1 = {0.f, 0.f, 0.f, 0.f}, G2 = {0.f, 0.f, 0.f, 0.f};               \
            G2 = MFMA(W2[0], b0, G2); G2 = MFMA(W2[1], b1, G2);                    \
            G1 = MFMA(W1[0], b0, G1); G1 = MFMA(W1[1], b1, G1);                    \
            float c2v, h2v;                                                        \
            act6(G2, c1, &c2v, &h2v);            /* uses c1 pre-update: P2(i-1) */ \
            part[(P) ^ 1][cw][quad][nl] = h2v * wo;                                \
            float hv;                                                              \
            act6(G1, c1, &c1, &hv);              /* P1(i): updates c1 */           \
            if (kh < HH) hbuf[(P) ^ 1][nl][1 + kh] = (_Float16)hv;                 \
        } else if (w == we) {                                                      \
            if ((DO_EMIT) && lane < RPB) {                                         \
                float s0 = bo, s1 = 0.f, s2 = 0.f, s3 = 0.f;                       \
                _Pragma("unroll")                                                  \
                for (int j = 0; j < 13; ++j) {                                     \
                    s0 += part[P][j][0][lane];                                     \
                    s1 += part[P][j][1][lane];                                     \
                    s2 += part[P][j][2][lane];                                     \
                    s3 += part[P][j][3][lane];                                     \
                }                                                                  \
                out[(size_t)(rb + lane) * TT + (EMIT_IDX)] = (s0 + s1) + (s2 + s3);\
            }                                                                      \
        } else if (w == wp && lane < RPB) {                                        \
            if ((XI) + 1 < TSEQ) hbuf[(P) ^ 1][lane][0] = (_Float16)xnext;         \
            if ((XI) + 2 < TSEQ) xnext = x[(size_t)(rb + lane) * TSEQ + (XI) + 2]; \
        }                                                                          \
        __syncthreads();                                                           \
    } while (0)

__global__ __launch_bounds__(NTH, 8)
void lstm_kernel(const float* __restrict__ x,
                 const float* __restrict__ Wih1, const float* __restrict__ Whh1,
                 const float* __restrict__ bih1, const float* __restrict__ bhh1,
                 const float* __restrict__ Wih2, const float* __restrict__ Whh2,
                 const float* __restrict__ bih2, const float* __restrict__ bhh2,
                 const float* __restrict__ Wout, const float* __restrict__ bout,
                 float* __restrict__ out)
{
    // double-buffered B-operand: [buf][row][k]; k=0: x_t, 1..51: h1, 52,53: const 1 (bias hi/lo)
    __shared__ _Float16 hbuf[2][RPB][HSTR];
    // per-(tile,quad) partials of wout.h2, double-buffered: [buf][tile][quad][row]
    __shared__ float part[2][13][4][17];
    __shared__ float wouts[64];

    const int tid  = threadIdx.x;
    const int lane = tid & 63;
    const int w    = tid >> 6;        // physical wave id (SIMD = w & 3)
    const int quad = lane >> 4;       // 0..3
    const int nl   = lane & 15;       // batch row (B-operand n / C-D col)
    const int rb   = blockIdx.x * RPB;

    // Role rotation: 13 compute waves split 4-3-3-3 over SIMDs; co-resident
    // blocks (b, b+256) use shifts 0 / 3 -> combined 7/6/6/7 per SIMD.
    const int  rot     = (blockIdx.x >> 8) & 1;
    const int  cw      = w - (rot ? 3 : 0);     // compute tile id if in [0,13)
    const bool is_comp = (cw >= 0) && (cw < 13);
    const int  we      = rot ? 0 : 13;          // emit wave
    const int  wp      = rot ? 1 : 14;          // x-prefetch wave

    // ---------------- one-time init ----------------
    if (tid < 64) wouts[tid] = (tid < HH) ? Wout[tid] : 0.0f;
    for (int i = tid; i < 2 * RPB * HSTR; i += NTH) (&hbuf[0][0][0])[i] = (_Float16)0.0f;
    __syncthreads();
    if (tid < RPB) {
        hbuf[0][tid][0]  = (_Float16)x[(size_t)(rb + tid) * TSEQ];
        hbuf[0][tid][52] = (_Float16)1.0f;  hbuf[0][tid][53] = (_Float16)1.0f;
        hbuf[1][tid][52] = (_Float16)1.0f;  hbuf[1][tid][53] = (_Float16)1.0f;
    }
    const float bo = bout[0];

    // ---------------- weight A-fragments in registers (once) ----------------
    // compute wave cw owns gate m-tile cw: rows j' = 16cw..16cw+15 (j' = 4k+q interleave)
    // Gate rows pre-scaled so MFMA emits exp2-ready args: i,f,o by -log2e, g by -2 log2e.
    h8 W1[2], W2[2];
    if (is_comp) {
        const int jp = 16 * cw + nl;
        const int kk = jp >> 2, q = jp & 3;
        const bool valid = (jp < H4);
        const int jrow = q * HH + kk;        // original gate row
        const float sc = (q == 2) ? (-2.0f * LOG2E) : (-LOG2E);
        float b1 = 0.0f, b2 = 0.0f;
        if (valid) { b1 = sc * (bih1[jrow] + bhh1[jrow]); b2 = sc * (bih2[jrow] + bhh2[jrow]); }
        const _Float16 b1h = (_Float16)b1, b2h = (_Float16)b2;
        const _Float16 b1l = (_Float16)(b1 - (float)b1h), b2l = (_Float16)(b2 - (float)b2h);
        #pragma unroll
        for (int s = 0; s < 2; ++s) {
            h8 w1v, w2v;
            #pragma unroll
            for (int j = 0; j < 8; ++j) {
                const int k = s * 32 + quad * 8 + j;
                _Float16 a1 = (_Float16)0.0f, a2 = (_Float16)0.0f;
                if (valid) {
                    if (k == 0) {
                        a1 = (_Float16)(sc * Wih1[jrow]);
                    } else if (k <= HH) {
                        const int o = jrow * HH + (k - 1);
                        a1 = (_Float16)(sc * Whh1[o]);
                        a2 = (_Float16)(sc * (Wih2[o] + Whh2[o]));
                    } else if (k == 52) { a1 = b1h; a2 = b2h; }
                    else if (k == 53)   { a1 = b1l; a2 = b2l; }
                }
                w1v[j] = a1;
                w2v[j] = a2;
            }
            W1[s] = w1v;
            W2[s] = w2v;
        }
    }

    // x register pipeline: at merged iteration i, write x(i+1), then load x(i+2)
    float xnext = 0.0f;
    if (w == wp && lane < RPB) xnext = x[(size_t)(rb + lane) * TSEQ + 1];

    const int kh = 4 * cw + quad;     // hidden unit owned by this lane (if is_comp)
    float c1 = 0.0f;
    __syncthreads();
    const float wo = is_comp ? wouts[kh] : 0.0f;

    // ---------------- peel i = 0 : P1(0) only ----------------
    if (is_comp) {
        const h8 b0 = *(const h8*)&hbuf[0][nl][quad * 8];
        const h8 b1 = *(const h8*)&hbuf[0][nl][32 + quad * 8];
        f4 G1 = {0.f, 0.f, 0.f, 0.f};
        G1 = MFMA(W1[0], b0, G1); G1 = MFMA(W1[1], b1, G1);
        float hv;
        act6(G1, c1, &c1, &hv);
        if (kh < HH) hbuf[1][nl][1 + kh] = (_Float16)hv;
    } else if (w == wp && lane < RPB) {
        hbuf[1][lane][0] = (_Float16)xnext;               // x(1)
        xnext = x[(size_t)(rb + lane) * TSEQ + 2];        // x(2)
    }
    __syncthreads();

    // ---------------- peel i = 1 : P2(0) + P1(1), nothing to emit yet ----------------
    MERGED_BODY(1, 0, false, 1);

    // ---------------- main: merged iterations i = 2 .. TSEQ-1, unrolled x2 ----------------
    for (int i = 2; i < TSEQ; i += 2) {
        MERGED_BODY(0, i - 2, true, i);
        MERGED_BODY(1, i - 1, true, i + 1);
    }
    // state: P1 done through 2047, P2 done through 2046,
    // out emitted through 2045; part[0] holds P2(2046).

    // ---------------- FUT tail: t = TSEQ-1 .. TT-1, explicit 3-phase ----------------
    for (int t = TSEQ - 1; t < TT; ++t) {
        const int pb = (t + 1) & 1;   // buffer holding h1 post-step-t (+ feedback x slot)
        if (is_comp) {
            // P2(t)
            const h8 b0 = *(const h8*)&hbuf[pb][nl][quad * 8];
            const h8 b1 = *(const h8*)&hbuf[pb][nl][32 + quad * 8];
            f4 G2 = {0.f, 0.f, 0.f, 0.f};
            G2 = MFMA(W2[0], b0, G2); G2 = MFMA(W2[1], b1, G2);
            float c2v, h2v;
            act6(G2, c1, &c2v, &h2v);
            part[t & 1][cw][quad][nl] = h2v * wo;
        } else if (w == we && t == TSEQ - 1 && lane < RPB) {
            // emit out(TSEQ-2) from part[0] (written during the last main iter)
            float s0 = bo, s1 = 0.f, s2 = 0.f, s3 = 0.f;
            #pragma unroll
            for (int j = 0; j < 13; ++j) {
                s0 += part[0][j][0][lane];
                s1 += part[0][j][1][lane];
                s2 += part[0][j][2][lane];
                s3 += part[0][j][3][lane];
            }
            out[(size_t)(rb + lane) * TT + (TSEQ - 2)] = (s0 + s1) + (s2 + s3);
        }
        __syncthreads();
        if (w == we && lane < RPB) {
            float s0 = bo, s1 = 0.f, s2 = 0.f, s3 = 0.f;
            #pragma unroll
            for (int j = 0; j < 13; ++j) {
                s0 += part[t & 1][j][0][lane];
                s1 += part[t & 1][j][1][lane];
                s2 += part[t & 1][j][2][lane];
                s3 += part[t & 1][j][3][lane];
            }
            const float s = (s0 + s1) + (s2 + s3);
            out[(size_t)(rb + lane) * TT + t] = s;
            if (t + 1 < TT) hbuf[pb][lane][0] = (_Float16)s;   // autoregressive x(t+1)
        }
        __syncthreads();
        if (t + 1 < TT) {
            if (is_comp) {
                // P1(t+1): reads hbuf[pb] (h1 post-t + feedback x), writes h1 post-(t+1)
                const h8 b0 = *(const h8*)&hbuf[pb][nl][quad * 8];
                const h8 b1 = *(const h8*)&hbuf[pb][nl][32 + quad * 8];
                f4 G1 = {0.f, 0.f, 0.f, 0.f};
                G1 = MFMA(W1[0], b0, G1); G1 = MFMA(W1[1], b1, G1);
                float hv;
                act6(G1, c1, &c1, &hv);
                if (kh < HH) hbuf[pb ^ 1][nl][1 + kh] = (_Float16)hv;
            }
            __syncthreads();
        }
    }
}

extern "C" void kernel_launch(void* const* d_in, const int* in_sizes, int n_in,
                              void* d_out, int out_size, void* d_ws, size_t ws_size,
                              hipStream_t stream) {
    (void)in_sizes; (void)n_in; (void)d_ws; (void)ws_size; (void)out_size;
    const float* x    = (const float*)d_in[0];
    const float* Wih1 = (const float*)d_in[1];
    const float* Whh1 = (const float*)d_in[2];
    const float* bih1 = (const float*)d_in[3];
    const float* bhh1 = (const float*)d_in[4];
    const float* Wih2 = (const float*)d_in[5];
    const float* Whh2 = (const float*)d_in[6];
    const float* bih2 = (const float*)d_in[7];
    const float* bhh2 = (const float*)d_in[8];
    const float* Wout = (const float*)d_in[9];
    const float* bout = (const float*)d_in[10];
    float* outp = (float*)d_out;

    dim3 grid(8192 / RPB);   // 512 blocks, 2 per CU
    dim3 block(NTH);
    hipLaunchKernelGGL(lstm_kernel, grid, block, 0, stream,
                       x, Wih1, Whh1, bih1, bhh1, Wih2, Whh2, bih2, bhh2,
                       Wout, bout, outp);
}